// Round 5
// baseline (87.410 us; speedup 1.0000x reference)
//
#include <hip/hip_runtime.h>
#include <math.h>

#define BB 4
#define CC 256
#define HH 48
#define WI 48
#define NN (HH*WI)      // 2304
#define NHEAD 8
#define HD 32
#define PLANE ((size_t)NN*HD)
#define BUF   (BB*NHEAD*NN*HD)      // 2359296 elems per [9216,256] buffer

typedef unsigned short u16;
typedef __attribute__((ext_vector_type(8))) short bf16x8;
typedef __attribute__((ext_vector_type(4))) float f32x4;

__device__ inline u16 f2bf(float f) {          // RNE float->bf16
  union { float f; unsigned u; } v; v.f = f;
  unsigned r = v.u + 0x7FFFu + ((v.u >> 16) & 1u);
  return (u16)(r >> 16);
}
__device__ inline u16 f2bf_rna(float f) {      // cheap round (f>=0)
  union { float f; unsigned u; } v; v.f = f;
  return (u16)((v.u + 0x8000u) >> 16);
}
__device__ inline ushort4 cvt4(float4 v) {
  ushort4 o = {f2bf(v.x), f2bf(v.y), f2bf(v.z), f2bf(v.w)};
  return o;
}

// ---------------------------------------------------------------------------
// Prep: XT[b*N+n][c] = bf16(x[b][c][n])  (transpose+convert via LDS tiles)
// ---------------------------------------------------------------------------
__global__ __launch_bounds__(256) void xt_kernel(
    const float* __restrict__ x, u16* __restrict__ XT) {
  __shared__ float T[32][36];
  const int n0 = blockIdx.x * 32, c0 = blockIdx.y * 32, b = blockIdx.z;
  const int t = threadIdx.x;
  const int c = t >> 3, n4 = (t & 7) * 4;
  *(float4*)&T[c][n4] = *(const float4*)&x[((size_t)b * CC + c0 + c) * NN + n0 + n4];
  __syncthreads();
  const int nn = t >> 3, c4 = (t & 7) * 4;
  ushort4 o;
  o.x = f2bf(T[c4 + 0][nn]); o.y = f2bf(T[c4 + 1][nn]);
  o.z = f2bf(T[c4 + 2][nn]); o.w = f2bf(T[c4 + 3][nn]);
  *(ushort4*)&XT[((size_t)b * NN + n0 + nn) * CC + c0 + c4] = o;
}

// ---------------------------------------------------------------------------
// Double-buffered MFMA GEMM core: D[128m][128j] = act[m][:] * W[j][:]^T, K=256.
// act bf16 row-major [.,256]; W fp32 row-major [.,256] (converted in staging).
// One barrier per K-step: issue next-step loads -> compute cur -> write next.
// Frag layout (HW-verified): A row=ll, B col=ll, k=lh*8+j; C/D row=lh*4+r, col=ll.
// ---------------------------------------------------------------------------
__device__ __forceinline__ void gemm_core_db(
    const u16* __restrict__ act, const float* __restrict__ wfp,
    int m0, int j0, u16 (&As)[2][128][40], u16 (&Ws)[2][128][40],
    f32x4 (&acc)[4][4], int tid) {
  const int lane = tid & 63, ll = lane & 15, lh = lane >> 4;
  const int wv = tid >> 6;
  const int wm = (wv >> 1) << 6, wj = (wv & 1) << 6;
  const int r_ = tid >> 1;             // staging row 0..127
  const int kh = (tid & 1) << 4;       // staging k-offset 0/16
  const size_t abase = (size_t)(m0 + r_) * CC + kh;
  const size_t wbase = (size_t)(j0 + r_) * CC + kh;

  // stage k-step 0 into buf 0
  {
    bf16x8 a0 = *(const bf16x8*)&act[abase];
    bf16x8 a1 = *(const bf16x8*)&act[abase + 8];
    float4 w0 = *(const float4*)&wfp[wbase];
    float4 w1 = *(const float4*)&wfp[wbase + 4];
    float4 w2 = *(const float4*)&wfp[wbase + 8];
    float4 w3 = *(const float4*)&wfp[wbase + 12];
    *(bf16x8*)&As[0][r_][kh]     = a0;
    *(bf16x8*)&As[0][r_][kh + 8] = a1;
    *(ushort4*)&Ws[0][r_][kh]      = cvt4(w0);
    *(ushort4*)&Ws[0][r_][kh + 4]  = cvt4(w1);
    *(ushort4*)&Ws[0][r_][kh + 8]  = cvt4(w2);
    *(ushort4*)&Ws[0][r_][kh + 12] = cvt4(w3);
  }
  __syncthreads();

#pragma unroll
  for (int step = 1; step <= 8; ++step) {
    const int cb = (step - 1) & 1, nb = step & 1;
    const bool pf = (step < 8);
    bf16x8 na0, na1; float4 nw0, nw1, nw2, nw3;
    if (pf) {
      const size_t ab = abase + step * 32, wb = wbase + step * 32;
      na0 = *(const bf16x8*)&act[ab];
      na1 = *(const bf16x8*)&act[ab + 8];
      nw0 = *(const float4*)&wfp[wb];
      nw1 = *(const float4*)&wfp[wb + 4];
      nw2 = *(const float4*)&wfp[wb + 8];
      nw3 = *(const float4*)&wfp[wb + 12];
    }
    bf16x8 af[4], bfv[4];
#pragma unroll
    for (int s = 0; s < 4; ++s) {
      af[s]  = *(const bf16x8*)&As[cb][wm + s * 16 + ll][lh * 8];
      bfv[s] = *(const bf16x8*)&Ws[cb][wj + s * 16 + ll][lh * 8];
    }
#pragma unroll
    for (int ms = 0; ms < 4; ++ms)
#pragma unroll
      for (int js = 0; js < 4; ++js)
        acc[ms][js] = __builtin_amdgcn_mfma_f32_16x16x32_bf16(af[ms], bfv[js], acc[ms][js], 0, 0, 0);
    if (pf) {
      *(bf16x8*)&As[nb][r_][kh]     = na0;
      *(bf16x8*)&As[nb][r_][kh + 8] = na1;
      *(ushort4*)&Ws[nb][r_][kh]      = cvt4(nw0);
      *(ushort4*)&Ws[nb][r_][kh + 4]  = cvt4(nw1);
      *(ushort4*)&Ws[nb][r_][kh + 8]  = cvt4(nw2);
      *(ushort4*)&Ws[nb][r_][kh + 12] = cvt4(nw3);
      __syncthreads();
    }
  }
}

// ---------------------------------------------------------------------------
// GEMM 1: qkv = XT @ W1^T + b1 -> Q[B,H,N,32], K[B,H,N,32], VT[B,H,32,N] (bf16)
// ---------------------------------------------------------------------------
__global__ __launch_bounds__(256) void qkv_gemm(
    const u16* __restrict__ XT, const float* __restrict__ w1,
    const float* __restrict__ bias,
    u16* __restrict__ Qb, u16* __restrict__ Kb, u16* __restrict__ VTb) {
  __shared__ u16 As[2][128][40];
  __shared__ u16 Ws[2][128][40];
  const int tid = threadIdx.x;
  const int m0 = blockIdx.x * 128, j0 = blockIdx.y * 128;
  f32x4 acc[4][4] = {};
  gemm_core_db(XT, w1, m0, j0, As, Ws, acc, tid);

  const int lane = tid & 63, ll = lane & 15, lh = lane >> 4;
  const int wv = tid >> 6;
  const int wm = (wv >> 1) << 6, wj = (wv & 1) << 6;
  const int part = blockIdx.y >> 1;            // 0=Q 1=K 2=V (uniform)
  const int b = m0 / NN, n0 = m0 % NN;
#pragma unroll
  for (int js = 0; js < 4; ++js) {
    const int j = j0 + wj + js * 16 + ll;
    const float bj = bias[j];
    const int head = (j >> 5) & 7, d = j & 31;
#pragma unroll
    for (int ms = 0; ms < 4; ++ms) {
      const int nb = n0 + wm + ms * 16 + (lh << 2);
      if (part == 2) {
        ushort4 v = {f2bf(acc[ms][js][0] + bj), f2bf(acc[ms][js][1] + bj),
                     f2bf(acc[ms][js][2] + bj), f2bf(acc[ms][js][3] + bj)};
        *(ushort4*)&VTb[(((size_t)b * NHEAD + head) * HD + d) * NN + nb] = v;
      } else {
        u16* dst = (part == 0 ? Qb : Kb) + ((size_t)b * NHEAD + head) * PLANE;
#pragma unroll
        for (int r = 0; r < 4; ++r)
          dst[(size_t)(nb + r) * HD + d] = f2bf(acc[ms][js][r] + bj);
      }
    }
  }
}

// ---------------------------------------------------------------------------
// MFMA windowed attention, 4-row chunked staging (2 barriers per 4 key-rows).
// Block = 256 thr (4 waves) per (b, head, 8x8 q-tile).
// ---------------------------------------------------------------------------
__global__ __launch_bounds__(256) void attn_mfma(
    const u16* __restrict__ Qb, const u16* __restrict__ Kb,
    const u16* __restrict__ VTb, u16* __restrict__ Ob) {
  __shared__ u16 Ks[128][40];     // [keyslot = rr*32+kk][dim]
  __shared__ u16 VTs[32][136];    // [dim][keyslot]
  __shared__ u16 Ps[4][16][136];  // per-wave P [q][keyslot]
  const int bid  = blockIdx.x;
  const int tile = bid % 36;
  const int head = (bid / 36) & 7;
  const int b    = bid / 288;
  const int th0 = (tile / 6) * 8, tw0 = (tile % 6) * 8;
  const int tid = threadIdx.x;
  const int wv = tid >> 6, lane = tid & 63;
  const int lh = lane >> 4, ll = lane & 15;
  const size_t plane = ((size_t)b * NHEAD + head) * PLANE;

  const int wlo = max(0, tw0 - 8);
  const int nw  = min(WI, tw0 + 16) - wlo;       // 16 or 24, block-uniform
  const int rlo = max(0, th0 - 8), rhi = min(HH, th0 + 16);

  const int qlA = (wv << 4) | ll;
  const int qhA = th0 + (qlA >> 3), qwA = tw0 + (qlA & 7);
  const bf16x8 qfrag = *(const bf16x8*)&Qb[plane + (size_t)(qhA * WI + qwA) * HD + lh * 8];

  int qh_r[4], qw_r[4];
  float cb0[4], cb1[4];
  const int wk0 = wlo + ll, wk1 = wlo + 16 + ll;
#pragma unroll
  for (int r = 0; r < 4; ++r) {
    int qq = (wv << 4) + (lh << 2) + r;
    qh_r[r] = th0 + (qq >> 3); qw_r[r] = tw0 + (qq & 7);
    cb0[r] = (wk0 < WI && abs(wk0 - qw_r[r]) <= 8) ? 0.0f : -30000.0f;
    cb1[r] = (wk1 < WI && abs(wk1 - qw_r[r]) <= 8) ? 0.0f : -30000.0f;
  }

  f32x4 o0 = {0.f, 0.f, 0.f, 0.f}, o1 = {0.f, 0.f, 0.f, 0.f};
  const f32x4 zf = {0.f, 0.f, 0.f, 0.f};
  float lsum[4] = {0.f, 0.f, 0.f, 0.f};
  const int myr_lo = th0 + (wv << 1) - 8;        // wave needs rows [lo,hi]
  const int myr_hi = th0 + (wv << 1) + 9;
  const int sk_key = tid >> 3, sk_d = (tid & 7) * 4;   // K staging
  const int sv_d   = tid >> 3, sv_k = (tid & 7) * 4;   // VT staging
  const ushort4 zz = {0, 0, 0, 0};
  const float C2 = 0.25501651847296056f;         // (1/sqrt(32)) * log2(e)

  const int nchunk = (rhi - rlo + 3) >> 2;
  for (int c = 0; c < nchunk; ++c) {
    const int c0 = rlo + (c << 2);
    __syncthreads();
#pragma unroll
    for (int rr = 0; rr < 4; ++rr) {
      const int hk = c0 + rr;
      if (hk < rhi) {
        ushort4 kv = zz, vv = zz;
        if (sk_key < nw)
          kv = *(const ushort4*)&Kb[plane + (size_t)(hk * WI + wlo + sk_key) * HD + sk_d];
        if (sv_k < nw)
          vv = *(const ushort4*)&VTb[plane + (size_t)sv_d * NN + hk * WI + wlo + sv_k];
        *(ushort4*)&Ks[(rr << 5) + sk_key][sk_d] = kv;
        *(ushort4*)&VTs[sv_d][(rr << 5) + sv_k] = vv;
      }
    }
    __syncthreads();
#pragma unroll
    for (int rr = 0; rr < 4; ++rr) {
      const int hk = c0 + rr;
      if (hk < myr_lo || hk > myr_hi || hk >= rhi) continue;   // wave-uniform
      const int ks = rr << 5;
      const bf16x8 k0 = *(const bf16x8*)&Ks[ks + ll][lh * 8];
      const bf16x8 k1 = *(const bf16x8*)&Ks[ks + 16 + ll][lh * 8];
      f32x4 s0 = __builtin_amdgcn_mfma_f32_16x16x32_bf16(qfrag, k0, zf, 0, 0, 0);
      f32x4 s1 = __builtin_amdgcn_mfma_f32_16x16x32_bf16(qfrag, k1, zf, 0, 0, 0);
#pragma unroll
      for (int r = 0; r < 4; ++r) {
        float rb = (hk >= qh_r[r] - 8 && hk <= qh_r[r] + 8) ? 0.0f : -30000.0f;
        float e0 = exp2f(fmaf(s0[r], C2, rb + cb0[r]));
        float e1 = exp2f(fmaf(s1[r], C2, rb + cb1[r]));
        lsum[r] += e0 + e1;
        Ps[wv][(lh << 2) + r][ks + ll]      = f2bf_rna(e0);
        Ps[wv][(lh << 2) + r][ks + 16 + ll] = f2bf_rna(e1);
      }
      const bf16x8 pa = *(const bf16x8*)&Ps[wv][ll][ks + lh * 8];
      const bf16x8 v0 = *(const bf16x8*)&VTs[ll][ks + lh * 8];
      const bf16x8 v1 = *(const bf16x8*)&VTs[16 + ll][ks + lh * 8];
      o0 = __builtin_amdgcn_mfma_f32_16x16x32_bf16(pa, v0, o0, 0, 0, 0);
      o1 = __builtin_amdgcn_mfma_f32_16x16x32_bf16(pa, v1, o1, 0, 0, 0);
    }
  }

#pragma unroll
  for (int r = 0; r < 4; ++r) {
    float s = lsum[r];
    s += __shfl_xor(s, 1); s += __shfl_xor(s, 2);
    s += __shfl_xor(s, 4); s += __shfl_xor(s, 8);
    const float inv = 1.0f / s;
    const size_t row = ((size_t)b * NN + qh_r[r] * WI + qw_r[r]) * CC + head * HD;
    Ob[row + ll]      = f2bf(o0[r] * inv);
    Ob[row + 16 + ll] = f2bf(o1[r] * inv);
  }
}

// ---------------------------------------------------------------------------
// GEMM 2: RES[m][c] = bf16( O @ W2^T + b2 + x[b][c][n] )
// ---------------------------------------------------------------------------
__global__ __launch_bounds__(256) void outproj_gemm(
    const u16* __restrict__ Ob, const float* __restrict__ w2,
    const float* __restrict__ bias, const float* __restrict__ x,
    u16* __restrict__ RESb) {
  __shared__ u16 As[2][128][40];
  __shared__ u16 Ws[2][128][40];
  const int tid = threadIdx.x;
  const int m0 = blockIdx.x * 128, j0 = blockIdx.y * 128;
  f32x4 acc[4][4] = {};
  gemm_core_db(Ob, w2, m0, j0, As, Ws, acc, tid);

  const int lane = tid & 63, ll = lane & 15, lh = lane >> 4;
  const int wv = tid >> 6;
  const int wm = (wv >> 1) << 6, wj = (wv & 1) << 6;
  const int b = m0 / NN, n0 = m0 % NN;
#pragma unroll
  for (int js = 0; js < 4; ++js) {
    const int j = j0 + wj + js * 16 + ll;
    const float bj = bias[j];
#pragma unroll
    for (int ms = 0; ms < 4; ++ms) {
      const int nb = n0 + wm + ms * 16 + (lh << 2);
      float4 xr = *(const float4*)&x[((size_t)b * CC + j) * NN + nb];
      float rr[4] = {acc[ms][js][0] + bj + xr.x, acc[ms][js][1] + bj + xr.y,
                     acc[ms][js][2] + bj + xr.z, acc[ms][js][3] + bj + xr.w};
#pragma unroll
      for (int r = 0; r < 4; ++r)
        RESb[(size_t)(m0 + wm + ms * 16 + (lh << 2) + r) * CC + j] = f2bf(rr[r]);
    }
  }
}

// ---------------------------------------------------------------------------
// GEMM 3: out[b][c][n] = relu( RES @ W3^T + b3 )   (fp32 output)
// ---------------------------------------------------------------------------
__global__ __launch_bounds__(256) void conv_gemm(
    const u16* __restrict__ RESb, const float* __restrict__ w3,
    const float* __restrict__ bias, float* __restrict__ out) {
  __shared__ u16 As[2][128][40];
  __shared__ u16 Ws[2][128][40];
  const int tid = threadIdx.x;
  const int m0 = blockIdx.x * 128, j0 = blockIdx.y * 128;
  f32x4 acc[4][4] = {};
  gemm_core_db(RESb, w3, m0, j0, As, Ws, acc, tid);

  const int lane = tid & 63, ll = lane & 15, lh = lane >> 4;
  const int wv = tid >> 6;
  const int wm = (wv >> 1) << 6, wj = (wv & 1) << 6;
  const int b = m0 / NN, n0 = m0 % NN;
#pragma unroll
  for (int js = 0; js < 4; ++js) {
    const int j = j0 + wj + js * 16 + ll;
    const float bj = bias[j];
#pragma unroll
    for (int ms = 0; ms < 4; ++ms) {
      const int nb = n0 + wm + ms * 16 + (lh << 2);
      float4 v;
      v.x = fmaxf(acc[ms][js][0] + bj, 0.0f);
      v.y = fmaxf(acc[ms][js][1] + bj, 0.0f);
      v.z = fmaxf(acc[ms][js][2] + bj, 0.0f);
      v.w = fmaxf(acc[ms][js][3] + bj, 0.0f);
      *(float4*)&out[((size_t)b * CC + j) * NN + nb] = v;
    }
  }
}

extern "C" void kernel_launch(void* const* d_in, const int* in_sizes, int n_in,
                              void* d_out, int out_size, void* d_ws, size_t ws_size,
                              hipStream_t stream) {
  const float* x         = (const float*)d_in[0];
  const float* in_proj_w = (const float*)d_in[1];
  const float* in_proj_b = (const float*)d_in[2];
  const float* out_w     = (const float*)d_in[3];
  const float* out_b     = (const float*)d_in[4];
  const float* conv_w    = (const float*)d_in[5];
  const float* conv_b    = (const float*)d_in[6];
  float* out = (float*)d_out;

  u16* wsb = (u16*)d_ws;
  u16* XT   = wsb;                         // [9216][256] bf16
  u16* Qb   = wsb + (size_t)BUF;           // [B,H,N,32]
  u16* Kb   = wsb + (size_t)2 * BUF;       // [B,H,N,32]
  u16* VTb  = wsb + (size_t)3 * BUF;       // [B,H,32,N]
  u16* Ob   = wsb + (size_t)4 * BUF;       // [9216][256]
  u16* RESb = wsb + (size_t)5 * BUF;       // [9216][256]

  xt_kernel<<<dim3(72, 8, 4), dim3(256), 0, stream>>>(x, XT);
  qkv_gemm<<<dim3(72, 6), dim3(256), 0, stream>>>(XT, in_proj_w, in_proj_b, Qb, Kb, VTb);
  attn_mfma<<<dim3(1152), dim3(256), 0, stream>>>(Qb, Kb, VTb, Ob);
  outproj_gemm<<<dim3(72, 2), dim3(256), 0, stream>>>(Ob, out_w, out_b, x, RESb);
  conv_gemm<<<dim3(72, 2), dim3(256), 0, stream>>>(RESb, conv_w, conv_b, out);
}

// Round 6
// 76.213 us; speedup vs baseline: 1.1469x; 1.1469x over previous
//
#include <hip/hip_runtime.h>
#include <math.h>

#define BB 4
#define CC 256
#define HH 48
#define WI 48
#define NN (HH*WI)      // 2304
#define NHEAD 8
#define HD 32
#define PLANE ((size_t)NN*HD)
#define BUF   (BB*NHEAD*NN*HD)      // 2359296 elems per [9216,256] buffer

typedef unsigned short u16;
typedef __attribute__((ext_vector_type(8))) short bf16x8;
typedef __attribute__((ext_vector_type(4))) float f32x4;

__device__ inline u16 f2bf(float f) {          // RNE float->bf16
  union { float f; unsigned u; } v; v.f = f;
  unsigned r = v.u + 0x7FFFu + ((v.u >> 16) & 1u);
  return (u16)(r >> 16);
}
__device__ inline u16 f2bf_rna(float f) {      // cheap round (f>=0)
  union { float f; unsigned u; } v; v.f = f;
  return (u16)((v.u + 0x8000u) >> 16);
}

// ---------------------------------------------------------------------------
// Prep 1: XT[b*N+n][c] = bf16(x[b][c][n])  (transpose+convert via LDS tiles)
// ---------------------------------------------------------------------------
__global__ __launch_bounds__(256) void xt_kernel(
    const float* __restrict__ x, u16* __restrict__ XT) {
  __shared__ float T[32][36];
  const int n0 = blockIdx.x * 32, c0 = blockIdx.y * 32, b = blockIdx.z;
  const int t = threadIdx.x;
  const int c = t >> 3, n4 = (t & 7) * 4;
  *(float4*)&T[c][n4] = *(const float4*)&x[((size_t)b * CC + c0 + c) * NN + n0 + n4];
  __syncthreads();
  const int nn = t >> 3, c4 = (t & 7) * 4;
  ushort4 o;
  o.x = f2bf(T[c4 + 0][nn]); o.y = f2bf(T[c4 + 1][nn]);
  o.z = f2bf(T[c4 + 2][nn]); o.w = f2bf(T[c4 + 3][nn]);
  *(ushort4*)&XT[((size_t)b * NN + n0 + nn) * CC + c0 + c4] = o;
}

// ---------------------------------------------------------------------------
// Prep 2: convert fp32 weights -> bf16 (W1 768x256, W2 256x256, W3 256x256)
// ---------------------------------------------------------------------------
__global__ __launch_bounds__(256) void wcvt_kernel(
    const float* __restrict__ w1, const float* __restrict__ w2,
    const float* __restrict__ w3, u16* __restrict__ W1b,
    u16* __restrict__ W2b, u16* __restrict__ W3b) {
  const int i = (blockIdx.x * 256 + threadIdx.x) * 4;
  const float* src; u16* dst; int off;
  if (i < 196608)      { src = w1; dst = W1b; off = i; }
  else if (i < 262144) { src = w2; dst = W2b; off = i - 196608; }
  else                 { src = w3; dst = W3b; off = i - 262144; }
  float4 v = *(const float4*)&src[off];
  ushort4 o = {f2bf(v.x), f2bf(v.y), f2bf(v.z), f2bf(v.w)};
  *(ushort4*)&dst[off] = o;
}

// ---------------------------------------------------------------------------
// Shared MFMA GEMM core (R4-proven): D[128m][128j] = act[m][k]*W[j][k]^T, K=256.
// 4 waves (2x2), 16x16x32 MFMA, single-buffered LDS (20.5 KB, high occupancy).
// Frag layout (HW-verified): A row=ll, B col=ll, k=lh*8+j; C/D row=lh*4+r, col=ll.
// ---------------------------------------------------------------------------
__device__ __forceinline__ void gemm_core(
    const u16* __restrict__ act, const u16* __restrict__ wb,
    int m0, int j0, u16 (&As)[128][40], u16 (&Ws)[128][40],
    f32x4 (&acc)[4][4], int tid) {
  const int lane = tid & 63, ll = lane & 15, lh = lane >> 4;
  const int wv = tid >> 6;
  const int wm = (wv >> 1) << 6, wj = (wv & 1) << 6;
  const int r_ = tid >> 1;             // staging row 0..127
  const int kh = (tid & 1) << 4;       // staging k-offset 0/16
  for (int k0 = 0; k0 < CC; k0 += 32) {
    __syncthreads();
    bf16x8 a0 = *(const bf16x8*)&act[(size_t)(m0 + r_) * CC + k0 + kh];
    bf16x8 a1 = *(const bf16x8*)&act[(size_t)(m0 + r_) * CC + k0 + kh + 8];
    bf16x8 w0 = *(const bf16x8*)&wb[(size_t)(j0 + r_) * CC + k0 + kh];
    bf16x8 w1 = *(const bf16x8*)&wb[(size_t)(j0 + r_) * CC + k0 + kh + 8];
    *(bf16x8*)&As[r_][kh]     = a0;
    *(bf16x8*)&As[r_][kh + 8] = a1;
    *(bf16x8*)&Ws[r_][kh]     = w0;
    *(bf16x8*)&Ws[r_][kh + 8] = w1;
    __syncthreads();
    bf16x8 af[4], bfv[4];
#pragma unroll
    for (int s = 0; s < 4; ++s) {
      af[s]  = *(const bf16x8*)&As[wm + s * 16 + ll][lh * 8];
      bfv[s] = *(const bf16x8*)&Ws[wj + s * 16 + ll][lh * 8];
    }
#pragma unroll
    for (int ms = 0; ms < 4; ++ms)
#pragma unroll
      for (int js = 0; js < 4; ++js)
        acc[ms][js] = __builtin_amdgcn_mfma_f32_16x16x32_bf16(af[ms], bfv[js], acc[ms][js], 0, 0, 0);
  }
}

// ---------------------------------------------------------------------------
// GEMM 1: qkv = XT @ W1^T + b1 -> Q[B,H,N,32], K[B,H,N,32], VT[B,H,32,N] (bf16)
// ---------------------------------------------------------------------------
__global__ __launch_bounds__(256) void qkv_gemm(
    const u16* __restrict__ XT, const u16* __restrict__ W1b,
    const float* __restrict__ bias,
    u16* __restrict__ Qb, u16* __restrict__ Kb, u16* __restrict__ VTb) {
  __shared__ u16 As[128][40];
  __shared__ u16 Ws[128][40];
  const int tid = threadIdx.x;
  const int m0 = blockIdx.x * 128, j0 = blockIdx.y * 128;
  f32x4 acc[4][4] = {};
  gemm_core(XT, W1b, m0, j0, As, Ws, acc, tid);

  const int lane = tid & 63, ll = lane & 15, lh = lane >> 4;
  const int wv = tid >> 6;
  const int wm = (wv >> 1) << 6, wj = (wv & 1) << 6;
  const int part = blockIdx.y >> 1;            // 0=Q 1=K 2=V (uniform)
  const int b = m0 / NN, n0 = m0 % NN;
#pragma unroll
  for (int js = 0; js < 4; ++js) {
    const int j = j0 + wj + js * 16 + ll;
    const float bj = bias[j];
    const int head = (j >> 5) & 7, d = j & 31;
#pragma unroll
    for (int ms = 0; ms < 4; ++ms) {
      const int nb = n0 + wm + ms * 16 + (lh << 2);
      if (part == 2) {
        ushort4 v = {f2bf(acc[ms][js][0] + bj), f2bf(acc[ms][js][1] + bj),
                     f2bf(acc[ms][js][2] + bj), f2bf(acc[ms][js][3] + bj)};
        *(ushort4*)&VTb[(((size_t)b * NHEAD + head) * HD + d) * NN + nb] = v;
      } else {
        u16* dst = (part == 0 ? Qb : Kb) + ((size_t)b * NHEAD + head) * PLANE;
#pragma unroll
        for (int r = 0; r < 4; ++r)
          dst[(size_t)(nb + r) * HD + d] = f2bf(acc[ms][js][r] + bj);
      }
    }
  }
}

// ---------------------------------------------------------------------------
// MFMA windowed attention, double-buffered per-row staging: ONE barrier per
// key-row, global loads issued a full row ahead (latency hidden under compute).
// LDS 14.3 KB -> still 8 blocks/CU (wave-limited). Block = 4 waves, 8x8 q-tile.
// ---------------------------------------------------------------------------
__global__ __launch_bounds__(256) void attn_mfma(
    const u16* __restrict__ Qb, const u16* __restrict__ Kb,
    const u16* __restrict__ VTb, u16* __restrict__ Ob) {
  __shared__ u16 Ks[2][32][32];   // [buf][key][dim]
  __shared__ u16 VTs[2][32][40];  // [buf][dim][key]
  __shared__ u16 Ps[4][16][40];   // per-wave P [q][key]
  const int bid  = blockIdx.x;
  const int tile = bid % 36;
  const int head = (bid / 36) & 7;
  const int b    = bid / 288;
  const int th0 = (tile / 6) * 8, tw0 = (tile % 6) * 8;
  const int tid = threadIdx.x;
  const int wv = tid >> 6, lane = tid & 63;
  const int lh = lane >> 4, ll = lane & 15;
  const size_t plane = ((size_t)b * NHEAD + head) * PLANE;

  const int wlo = max(0, tw0 - 8);
  const int nw  = min(WI, tw0 + 16) - wlo;       // 16 or 24, block-uniform
  const int rlo = max(0, th0 - 8), rhi = min(HH, th0 + 16);

  const int qlA = (wv << 4) | ll;
  const int qhA = th0 + (qlA >> 3), qwA = tw0 + (qlA & 7);
  const bf16x8 qfrag = *(const bf16x8*)&Qb[plane + (size_t)(qhA * WI + qwA) * HD + lh * 8];

  int qh_r[4], qw_r[4];
  float cb0[4], cb1[4];
  const int wk0 = wlo + ll, wk1 = wlo + 16 + ll;
#pragma unroll
  for (int r = 0; r < 4; ++r) {
    int qq = (wv << 4) + (lh << 2) + r;
    qh_r[r] = th0 + (qq >> 3); qw_r[r] = tw0 + (qq & 7);
    cb0[r] = (wk0 < WI && abs(wk0 - qw_r[r]) <= 8) ? 0.0f : -30000.0f;
    cb1[r] = (wk1 < WI && abs(wk1 - qw_r[r]) <= 8) ? 0.0f : -30000.0f;
  }

  f32x4 o0 = {0.f, 0.f, 0.f, 0.f}, o1 = {0.f, 0.f, 0.f, 0.f};
  const f32x4 zf = {0.f, 0.f, 0.f, 0.f};
  float lsum[4] = {0.f, 0.f, 0.f, 0.f};
  const int myr_lo = th0 + (wv << 1) - 8;        // wave needs rows [lo,hi]
  const int myr_hi = th0 + (wv << 1) + 9;
  const int sk_key = tid >> 3, sk_d = (tid & 7) * 4;   // K staging
  const int sv_d   = tid >> 3, sv_k = (tid & 7) * 4;   // VT staging
  const ushort4 zz = {0, 0, 0, 0};
  const float C2 = 0.25501651847296056f;         // (1/sqrt(32)) * log2(e)

  // prefetch + stage first row into buf 0
  {
    ushort4 kv = zz, vv = zz;
    if (sk_key < nw)
      kv = *(const ushort4*)&Kb[plane + (size_t)(rlo * WI + wlo + sk_key) * HD + sk_d];
    if (sv_k < nw)
      vv = *(const ushort4*)&VTb[plane + (size_t)sv_d * NN + rlo * WI + wlo + sv_k];
    *(ushort4*)&Ks[0][sk_key][sk_d] = kv;
    *(ushort4*)&VTs[0][sv_d][sv_k] = vv;
  }

  int cur = 0;
  for (int hk = rlo; hk < rhi; ++hk) {
    // issue next row's global loads (consumed after compute)
    ushort4 nkv = zz, nvv = zz;
    const bool more = (hk + 1 < rhi);
    if (more) {
      if (sk_key < nw)
        nkv = *(const ushort4*)&Kb[plane + (size_t)((hk + 1) * WI + wlo + sk_key) * HD + sk_d];
      if (sv_k < nw)
        nvv = *(const ushort4*)&VTb[plane + (size_t)sv_d * NN + (hk + 1) * WI + wlo + sv_k];
    }
    __syncthreads();   // buf[cur] fully written (by prev iteration's tail)
    if (hk >= myr_lo && hk <= myr_hi) {          // wave-uniform
      const bf16x8 k0 = *(const bf16x8*)&Ks[cur][ll][lh * 8];
      const bf16x8 k1 = *(const bf16x8*)&Ks[cur][16 + ll][lh * 8];
      f32x4 s0 = __builtin_amdgcn_mfma_f32_16x16x32_bf16(qfrag, k0, zf, 0, 0, 0);
      f32x4 s1 = __builtin_amdgcn_mfma_f32_16x16x32_bf16(qfrag, k1, zf, 0, 0, 0);
#pragma unroll
      for (int r = 0; r < 4; ++r) {
        float rb = (hk >= qh_r[r] - 8 && hk <= qh_r[r] + 8) ? 0.0f : -30000.0f;
        float e0 = exp2f(fmaf(s0[r], C2, rb + cb0[r]));
        float e1 = exp2f(fmaf(s1[r], C2, rb + cb1[r]));
        lsum[r] += e0 + e1;
        Ps[wv][(lh << 2) + r][ll]      = f2bf_rna(e0);
        Ps[wv][(lh << 2) + r][16 + ll] = f2bf_rna(e1);
      }
      const bf16x8 pa = *(const bf16x8*)&Ps[wv][ll][lh * 8];
      const bf16x8 v0 = *(const bf16x8*)&VTs[cur][ll][lh * 8];
      const bf16x8 v1 = *(const bf16x8*)&VTs[cur][16 + ll][lh * 8];
      o0 = __builtin_amdgcn_mfma_f32_16x16x32_bf16(pa, v0, o0, 0, 0, 0);
      o1 = __builtin_amdgcn_mfma_f32_16x16x32_bf16(pa, v1, o1, 0, 0, 0);
    }
    if (more) {
      *(ushort4*)&Ks[cur ^ 1][sk_key][sk_d] = nkv;
      *(ushort4*)&VTs[cur ^ 1][sv_d][sv_k] = nvv;
    }
    cur ^= 1;
  }

#pragma unroll
  for (int r = 0; r < 4; ++r) {
    float s = lsum[r];
    s += __shfl_xor(s, 1); s += __shfl_xor(s, 2);
    s += __shfl_xor(s, 4); s += __shfl_xor(s, 8);
    const float inv = 1.0f / s;
    const size_t row = ((size_t)b * NN + qh_r[r] * WI + qw_r[r]) * CC + head * HD;
    Ob[row + ll]      = f2bf(o0[r] * inv);
    Ob[row + 16 + ll] = f2bf(o1[r] * inv);
  }
}

// ---------------------------------------------------------------------------
// GEMM 2: RES[m][c] = bf16( O @ W2^T + b2 + x[b][c][n] )
// ---------------------------------------------------------------------------
__global__ __launch_bounds__(256) void outproj_gemm(
    const u16* __restrict__ Ob, const u16* __restrict__ W2b,
    const float* __restrict__ bias, const float* __restrict__ x,
    u16* __restrict__ RESb) {
  __shared__ u16 As[128][40];
  __shared__ u16 Ws[128][40];
  const int tid = threadIdx.x;
  const int m0 = blockIdx.x * 128, j0 = blockIdx.y * 128;
  f32x4 acc[4][4] = {};
  gemm_core(Ob, W2b, m0, j0, As, Ws, acc, tid);

  const int lane = tid & 63, ll = lane & 15, lh = lane >> 4;
  const int wv = tid >> 6;
  const int wm = (wv >> 1) << 6, wj = (wv & 1) << 6;
  const int b = m0 / NN, n0 = m0 % NN;
#pragma unroll
  for (int js = 0; js < 4; ++js) {
    const int j = j0 + wj + js * 16 + ll;
    const float bj = bias[j];
#pragma unroll
    for (int ms = 0; ms < 4; ++ms) {
      const int nb = n0 + wm + ms * 16 + (lh << 2);
      float4 xr = *(const float4*)&x[((size_t)b * CC + j) * NN + nb];
      float rr[4] = {acc[ms][js][0] + bj + xr.x, acc[ms][js][1] + bj + xr.y,
                     acc[ms][js][2] + bj + xr.z, acc[ms][js][3] + bj + xr.w};
#pragma unroll
      for (int r = 0; r < 4; ++r)
        RESb[(size_t)(m0 + wm + ms * 16 + (lh << 2) + r) * CC + j] = f2bf(rr[r]);
    }
  }
}

// ---------------------------------------------------------------------------
// GEMM 3: out[b][c][n] = relu( RES @ W3^T + b3 )   (fp32 output)
// ---------------------------------------------------------------------------
__global__ __launch_bounds__(256) void conv_gemm(
    const u16* __restrict__ RESb, const u16* __restrict__ W3b,
    const float* __restrict__ bias, float* __restrict__ out) {
  __shared__ u16 As[128][40];
  __shared__ u16 Ws[128][40];
  const int tid = threadIdx.x;
  const int m0 = blockIdx.x * 128, j0 = blockIdx.y * 128;
  f32x4 acc[4][4] = {};
  gemm_core(RESb, W3b, m0, j0, As, Ws, acc, tid);

  const int lane = tid & 63, ll = lane & 15, lh = lane >> 4;
  const int wv = tid >> 6;
  const int wm = (wv >> 1) << 6, wj = (wv & 1) << 6;
  const int b = m0 / NN, n0 = m0 % NN;
#pragma unroll
  for (int js = 0; js < 4; ++js) {
    const int j = j0 + wj + js * 16 + ll;
    const float bj = bias[j];
#pragma unroll
    for (int ms = 0; ms < 4; ++ms) {
      const int nb = n0 + wm + ms * 16 + (lh << 2);
      float4 v;
      v.x = fmaxf(acc[ms][js][0] + bj, 0.0f);
      v.y = fmaxf(acc[ms][js][1] + bj, 0.0f);
      v.z = fmaxf(acc[ms][js][2] + bj, 0.0f);
      v.w = fmaxf(acc[ms][js][3] + bj, 0.0f);
      *(float4*)&out[((size_t)b * CC + j) * NN + nb] = v;
    }
  }
}

extern "C" void kernel_launch(void* const* d_in, const int* in_sizes, int n_in,
                              void* d_out, int out_size, void* d_ws, size_t ws_size,
                              hipStream_t stream) {
  const float* x         = (const float*)d_in[0];
  const float* in_proj_w = (const float*)d_in[1];
  const float* in_proj_b = (const float*)d_in[2];
  const float* out_w     = (const float*)d_in[3];
  const float* out_b     = (const float*)d_in[4];
  const float* conv_w    = (const float*)d_in[5];
  const float* conv_b    = (const float*)d_in[6];
  float* out = (float*)d_out;

  u16* wsb = (u16*)d_ws;
  u16* XT   = wsb;                         // [9216][256] bf16
  u16* Qb   = wsb + (size_t)BUF;           // [B,H,N,32]
  u16* Kb   = wsb + (size_t)2 * BUF;       // [B,H,N,32]
  u16* VTb  = wsb + (size_t)3 * BUF;       // [B,H,32,N]
  u16* Ob   = wsb + (size_t)4 * BUF;       // [9216][256]
  u16* RESb = wsb + (size_t)5 * BUF;       // [9216][256]
  u16* W1b  = wsb + (size_t)6 * BUF;       // [768][256]
  u16* W2b  = W1b + 196608;                // [256][256]
  u16* W3b  = W2b + 65536;                 // [256][256]

  xt_kernel<<<dim3(72, 8, 4), dim3(256), 0, stream>>>(x, XT);
  wcvt_kernel<<<dim3(320), dim3(256), 0, stream>>>(in_proj_w, out_w, conv_w, W1b, W2b, W3b);
  qkv_gemm<<<dim3(72, 6), dim3(256), 0, stream>>>(XT, W1b, in_proj_b, Qb, Kb, VTb);
  attn_mfma<<<dim3(1152), dim3(256), 0, stream>>>(Qb, Kb, VTb, Ob);
  outproj_gemm<<<dim3(72, 2), dim3(256), 0, stream>>>(Ob, W2b, out_b, x, RESb);
  conv_gemm<<<dim3(72, 2), dim3(256), 0, stream>>>(RESb, W3b, conv_b, out);
}

// Round 8
// 65.924 us; speedup vs baseline: 1.3259x; 1.1561x over previous
//
#include <hip/hip_runtime.h>
#include <math.h>

#define BB 4
#define CC 256
#define HH 48
#define WI 48
#define NN (HH*WI)      // 2304
#define NHEAD 8
#define HD 32
#define PLANE ((size_t)NN*HD)
#define BUF   (BB*NHEAD*NN*HD)      // 2359296 elems per [9216,256] buffer

typedef unsigned short u16;
typedef __attribute__((ext_vector_type(8))) short bf16x8;
typedef __attribute__((ext_vector_type(4))) float f32x4;

__device__ inline u16 f2bf(float f) {          // RNE float->bf16
  union { float f; unsigned u; } v; v.f = f;
  unsigned r = v.u + 0x7FFFu + ((v.u >> 16) & 1u);
  return (u16)(r >> 16);
}
__device__ inline u16 f2bf_rna(float f) {      // cheap round (f>=0)
  union { float f; unsigned u; } v; v.f = f;
  return (u16)((v.u + 0x8000u) >> 16);
}

// ---------------------------------------------------------------------------
// Fused prep: blocks [0,2304): XT[b*N+n][c] = bf16(x[b][c][n]) transpose tiles
//             blocks [2304,2624): fp32->bf16 weight convert (W1|W2|W3)
// ---------------------------------------------------------------------------
__global__ __launch_bounds__(256) void prep_kernel(
    const float* __restrict__ x, const float* __restrict__ w1,
    const float* __restrict__ w2, const float* __restrict__ w3,
    u16* __restrict__ XT, u16* __restrict__ W1b,
    u16* __restrict__ W2b, u16* __restrict__ W3b) {
  __shared__ float T[32][36];
  const int bx = blockIdx.x;
  const int t = threadIdx.x;
  if (bx < 2304) {
    const int n0 = (bx % 72) * 32, c0 = ((bx / 72) & 7) * 32, b = bx / 576;
    const int c = t >> 3, n4 = (t & 7) * 4;
    *(float4*)&T[c][n4] = *(const float4*)&x[((size_t)b * CC + c0 + c) * NN + n0 + n4];
    __syncthreads();
    const int nn = t >> 3, c4 = (t & 7) * 4;
    ushort4 o;
    o.x = f2bf(T[c4 + 0][nn]); o.y = f2bf(T[c4 + 1][nn]);
    o.z = f2bf(T[c4 + 2][nn]); o.w = f2bf(T[c4 + 3][nn]);
    *(ushort4*)&XT[((size_t)b * NN + n0 + nn) * CC + c0 + c4] = o;
  } else {
    const int i = ((bx - 2304) * 256 + t) * 4;
    const float* src; u16* dst; int off;
    if (i < 196608)      { src = w1; dst = W1b; off = i; }
    else if (i < 262144) { src = w2; dst = W2b; off = i - 196608; }
    else                 { src = w3; dst = W3b; off = i - 262144; }
    float4 v = *(const float4*)&src[off];
    ushort4 o = {f2bf(v.x), f2bf(v.y), f2bf(v.z), f2bf(v.w)};
    *(ushort4*)&dst[off] = o;
  }
}

// ---------------------------------------------------------------------------
// MFMA GEMM core 128x128 (R4-proven, used by qkv): K=256, 4 waves 2x2.
// Frag layout (HW-verified): A row=ll, B col=ll, k=lh*8+j (lh=lane>>4 in 0..3);
// C/D row=lh*4+r, col=ll.
// ---------------------------------------------------------------------------
__device__ __forceinline__ void gemm_core(
    const u16* __restrict__ act, const u16* __restrict__ wb,
    int m0, int j0, u16 (&As)[128][40], u16 (&Ws)[128][40],
    f32x4 (&acc)[4][4], int tid) {
  const int lane = tid & 63, ll = lane & 15, lh = lane >> 4;
  const int wv = tid >> 6;
  const int wm = (wv >> 1) << 6, wj = (wv & 1) << 6;
  const int r_ = tid >> 1;
  const int kh = (tid & 1) << 4;
  for (int k0 = 0; k0 < CC; k0 += 32) {
    __syncthreads();
    bf16x8 a0 = *(const bf16x8*)&act[(size_t)(m0 + r_) * CC + k0 + kh];
    bf16x8 a1 = *(const bf16x8*)&act[(size_t)(m0 + r_) * CC + k0 + kh + 8];
    bf16x8 w0 = *(const bf16x8*)&wb[(size_t)(j0 + r_) * CC + k0 + kh];
    bf16x8 w1 = *(const bf16x8*)&wb[(size_t)(j0 + r_) * CC + k0 + kh + 8];
    *(bf16x8*)&As[r_][kh]     = a0;
    *(bf16x8*)&As[r_][kh + 8] = a1;
    *(bf16x8*)&Ws[r_][kh]     = w0;
    *(bf16x8*)&Ws[r_][kh + 8] = w1;
    __syncthreads();
    bf16x8 af[4], bfv[4];
#pragma unroll
    for (int s = 0; s < 4; ++s) {
      af[s]  = *(const bf16x8*)&As[wm + s * 16 + ll][lh * 8];
      bfv[s] = *(const bf16x8*)&Ws[wj + s * 16 + ll][lh * 8];
    }
#pragma unroll
    for (int ms = 0; ms < 4; ++ms)
#pragma unroll
      for (int js = 0; js < 4; ++js)
        acc[ms][js] = __builtin_amdgcn_mfma_f32_16x16x32_bf16(af[ms], bfv[js], acc[ms][js], 0, 0, 0);
  }
}

// ---------------------------------------------------------------------------
// MFMA GEMM core 64x64 (outproj/conv: 4x more blocks -> latency hiding).
// 4 waves 2x2, each wave 32x32 (2x2 frags). LDS 10 KB.
// Staging: 128 thr/operand, 16 elems each (BOTH bf16x8 halves — R7 bugfix).
// ---------------------------------------------------------------------------
__device__ __forceinline__ void gemm_core64(
    const u16* __restrict__ act, const u16* __restrict__ wb,
    int m0, int j0, u16 (&As)[64][40], u16 (&Ws)[64][40],
    f32x4 (&acc)[2][2], int tid) {
  const int lane = tid & 63, ll = lane & 15, lh = lane >> 4;
  const int wv = tid >> 6;
  const int wm = (wv >> 1) << 5, wj = (wv & 1) << 5;
  const bool isW = (tid >= 128);
  const int r_ = (tid & 127) >> 1;
  const int kh = (tid & 1) << 4;
  const u16* src = isW ? &wb[(size_t)(j0 + r_) * CC + kh]
                       : &act[(size_t)(m0 + r_) * CC + kh];
  u16* dst = isW ? &Ws[r_][kh] : &As[r_][kh];
  for (int k0 = 0; k0 < CC; k0 += 32) {
    __syncthreads();
    bf16x8 v0 = *(const bf16x8*)(src + k0);
    bf16x8 v1 = *(const bf16x8*)(src + k0 + 8);
    *(bf16x8*)dst       = v0;
    *(bf16x8*)(dst + 8) = v1;
    __syncthreads();
    bf16x8 af[2], bfv[2];
#pragma unroll
    for (int s = 0; s < 2; ++s) {
      af[s]  = *(const bf16x8*)&As[wm + s * 16 + ll][lh * 8];
      bfv[s] = *(const bf16x8*)&Ws[wj + s * 16 + ll][lh * 8];
    }
#pragma unroll
    for (int ms = 0; ms < 2; ++ms)
#pragma unroll
      for (int js = 0; js < 2; ++js)
        acc[ms][js] = __builtin_amdgcn_mfma_f32_16x16x32_bf16(af[ms], bfv[js], acc[ms][js], 0, 0, 0);
  }
}

// ---------------------------------------------------------------------------
// GEMM 1: qkv = XT @ W1^T + b1 -> Q[B,H,N,32], K[B,H,N,32], VT[B,H,32,N] (bf16)
// ---------------------------------------------------------------------------
__global__ __launch_bounds__(256) void qkv_gemm(
    const u16* __restrict__ XT, const u16* __restrict__ W1b,
    const float* __restrict__ bias,
    u16* __restrict__ Qb, u16* __restrict__ Kb, u16* __restrict__ VTb) {
  __shared__ u16 As[128][40];
  __shared__ u16 Ws[128][40];
  const int tid = threadIdx.x;
  const int m0 = blockIdx.x * 128, j0 = blockIdx.y * 128;
  f32x4 acc[4][4] = {};
  gemm_core(XT, W1b, m0, j0, As, Ws, acc, tid);

  const int lane = tid & 63, ll = lane & 15, lh = lane >> 4;
  const int wv = tid >> 6;
  const int wm = (wv >> 1) << 6, wj = (wv & 1) << 6;
  const int part = blockIdx.y >> 1;            // 0=Q 1=K 2=V (uniform)
  const int b = m0 / NN, n0 = m0 % NN;
#pragma unroll
  for (int js = 0; js < 4; ++js) {
    const int j = j0 + wj + js * 16 + ll;
    const float bj = bias[j];
    const int head = (j >> 5) & 7, d = j & 31;
#pragma unroll
    for (int ms = 0; ms < 4; ++ms) {
      const int nb = n0 + wm + ms * 16 + (lh << 2);
      if (part == 2) {
        ushort4 v = {f2bf(acc[ms][js][0] + bj), f2bf(acc[ms][js][1] + bj),
                     f2bf(acc[ms][js][2] + bj), f2bf(acc[ms][js][3] + bj)};
        *(ushort4*)&VTb[(((size_t)b * NHEAD + head) * HD + d) * NN + nb] = v;
      } else {
        u16* dst = (part == 0 ? Qb : Kb) + ((size_t)b * NHEAD + head) * PLANE;
#pragma unroll
        for (int r = 0; r < 4; ++r)
          dst[(size_t)(nb + r) * HD + d] = f2bf(acc[ms][js][r] + bj);
      }
    }
  }
}

// ---------------------------------------------------------------------------
// MFMA windowed attention, double-buffered per-row staging (R6-proven) +
// nw==16 fast path + hoisted row-bias.
// ---------------------------------------------------------------------------
__global__ __launch_bounds__(256) void attn_mfma(
    const u16* __restrict__ Qb, const u16* __restrict__ Kb,
    const u16* __restrict__ VTb, u16* __restrict__ Ob) {
  __shared__ u16 Ks[2][32][32];   // [buf][key][dim]
  __shared__ u16 VTs[2][32][40];  // [buf][dim][key]
  __shared__ u16 Ps[4][16][40];   // per-wave P [q][key]
  const int bid  = blockIdx.x;
  const int tile = bid % 36;
  const int head = (bid / 36) & 7;
  const int b    = bid / 288;
  const int th0 = (tile / 6) * 8, tw0 = (tile % 6) * 8;
  const int tid = threadIdx.x;
  const int wv = tid >> 6, lane = tid & 63;
  const int lh = lane >> 4, ll = lane & 15;
  const size_t plane = ((size_t)b * NHEAD + head) * PLANE;

  const int wlo = max(0, tw0 - 8);
  const int nw  = min(WI, tw0 + 16) - wlo;       // 16 or 24, block-uniform
  const bool nw24 = (nw > 16);
  const int rlo = max(0, th0 - 8), rhi = min(HH, th0 + 16);

  const int qlA = (wv << 4) | ll;
  const int qhA = th0 + (qlA >> 3), qwA = tw0 + (qlA & 7);
  const bf16x8 qfrag = *(const bf16x8*)&Qb[plane + (size_t)(qhA * WI + qwA) * HD + lh * 8];

  // all 4 C/D rows of a lane share one spatial query row
  const int qh0 = th0 + (((wv << 4) + (lh << 2)) >> 3);
  int qw_r[4];
  float cb0[4], cb1[4];
  const int wk0 = wlo + ll, wk1 = wlo + 16 + ll;
#pragma unroll
  for (int r = 0; r < 4; ++r) {
    int qq = (wv << 4) + (lh << 2) + r;
    qw_r[r] = tw0 + (qq & 7);
    cb0[r] = (abs(wk0 - qw_r[r]) <= 8) ? 0.0f : -30000.0f;
    cb1[r] = (wk1 < WI && abs(wk1 - qw_r[r]) <= 8) ? 0.0f : -30000.0f;
  }

  // nw==16: key slots 16..31 always masked -> zero their P entries once
  if (!nw24) {
#pragma unroll
    for (int r = 0; r < 4; ++r)
      Ps[wv][(lh << 2) + r][16 + ll] = 0;
  }

  f32x4 o0 = {0.f, 0.f, 0.f, 0.f}, o1 = {0.f, 0.f, 0.f, 0.f};
  const f32x4 zf = {0.f, 0.f, 0.f, 0.f};
  float lsum[4] = {0.f, 0.f, 0.f, 0.f};
  const int myr_lo = th0 + (wv << 1) - 8;
  const int myr_hi = th0 + (wv << 1) + 9;
  const int sk_key = tid >> 3, sk_d = (tid & 7) * 4;   // K staging
  const int sv_d   = tid >> 3, sv_k = (tid & 7) * 4;   // VT staging
  const ushort4 zz = {0, 0, 0, 0};
  const float C2 = 0.25501651847296056f;         // (1/sqrt(32)) * log2(e)

  // stage first row into buf 0
  {
    ushort4 kv = zz, vv = zz;
    if (sk_key < nw)
      kv = *(const ushort4*)&Kb[plane + (size_t)(rlo * WI + wlo + sk_key) * HD + sk_d];
    if (sv_k < nw)
      vv = *(const ushort4*)&VTb[plane + (size_t)sv_d * NN + rlo * WI + wlo + sv_k];
    *(ushort4*)&Ks[0][sk_key][sk_d] = kv;
    *(ushort4*)&VTs[0][sv_d][sv_k] = vv;
  }

  int cur = 0;
  for (int hk = rlo; hk < rhi; ++hk) {
    ushort4 nkv = zz, nvv = zz;
    const bool more = (hk + 1 < rhi);
    if (more) {
      if (sk_key < nw)
        nkv = *(const ushort4*)&Kb[plane + (size_t)((hk + 1) * WI + wlo + sk_key) * HD + sk_d];
      if (sv_k < nw)
        nvv = *(const ushort4*)&VTb[plane + (size_t)sv_d * NN + (hk + 1) * WI + wlo + sv_k];
    }
    __syncthreads();   // buf[cur] complete
    if (hk >= myr_lo && hk <= myr_hi) {            // wave-uniform
      const float rb = (hk >= qh0 - 8 && hk <= qh0 + 8) ? 0.0f : -30000.0f;
      const bf16x8 k0 = *(const bf16x8*)&Ks[cur][ll][lh * 8];
      f32x4 s0 = __builtin_amdgcn_mfma_f32_16x16x32_bf16(qfrag, k0, zf, 0, 0, 0);
      if (nw24) {
        const bf16x8 k1 = *(const bf16x8*)&Ks[cur][16 + ll][lh * 8];
        f32x4 s1 = __builtin_amdgcn_mfma_f32_16x16x32_bf16(qfrag, k1, zf, 0, 0, 0);
#pragma unroll
        for (int r = 0; r < 4; ++r) {
          float e0 = exp2f(fmaf(s0[r], C2, rb + cb0[r]));
          float e1 = exp2f(fmaf(s1[r], C2, rb + cb1[r]));
          lsum[r] += e0 + e1;
          Ps[wv][(lh << 2) + r][ll]      = f2bf_rna(e0);
          Ps[wv][(lh << 2) + r][16 + ll] = f2bf_rna(e1);
        }
      } else {
#pragma unroll
        for (int r = 0; r < 4; ++r) {
          float e0 = exp2f(fmaf(s0[r], C2, rb + cb0[r]));
          lsum[r] += e0;
          Ps[wv][(lh << 2) + r][ll] = f2bf_rna(e0);
        }
      }
      const bf16x8 pa = *(const bf16x8*)&Ps[wv][ll][lh * 8];
      const bf16x8 v0 = *(const bf16x8*)&VTs[cur][ll][lh * 8];
      const bf16x8 v1 = *(const bf16x8*)&VTs[cur][16 + ll][lh * 8];
      o0 = __builtin_amdgcn_mfma_f32_16x16x32_bf16(pa, v0, o0, 0, 0, 0);
      o1 = __builtin_amdgcn_mfma_f32_16x16x32_bf16(pa, v1, o1, 0, 0, 0);
    }
    if (more) {
      *(ushort4*)&Ks[cur ^ 1][sk_key][sk_d] = nkv;
      *(ushort4*)&VTs[cur ^ 1][sv_d][sv_k] = nvv;
    }
    cur ^= 1;
  }

#pragma unroll
  for (int r = 0; r < 4; ++r) {
    float s = lsum[r];
    s += __shfl_xor(s, 1); s += __shfl_xor(s, 2);
    s += __shfl_xor(s, 4); s += __shfl_xor(s, 8);
    const float inv = 1.0f / s;
    const size_t row = ((size_t)b * NN + qh0 * WI + qw_r[r]) * CC + head * HD;
    Ob[row + ll]      = f2bf(o0[r] * inv);
    Ob[row + 16 + ll] = f2bf(o1[r] * inv);
  }
}

// ---------------------------------------------------------------------------
// GEMM 2 (64x64 tiles): RES[m][c] = bf16( O @ W2^T + b2 + x[b][c][n] )
// ---------------------------------------------------------------------------
__global__ __launch_bounds__(256) void outproj_gemm(
    const u16* __restrict__ Ob, const u16* __restrict__ W2b,
    const float* __restrict__ bias, const float* __restrict__ x,
    u16* __restrict__ RESb) {
  __shared__ u16 As[64][40];
  __shared__ u16 Ws[64][40];
  const int tid = threadIdx.x;
  const int m0 = blockIdx.x * 64, j0 = blockIdx.y * 64;
  f32x4 acc[2][2] = {};
  gemm_core64(Ob, W2b, m0, j0, As, Ws, acc, tid);

  const int lane = tid & 63, ll = lane & 15, lh = lane >> 4;
  const int wv = tid >> 6;
  const int wm = (wv >> 1) << 5, wj = (wv & 1) << 5;
  const int b = m0 / NN, n0 = m0 % NN;
#pragma unroll
  for (int js = 0; js < 2; ++js) {
    const int j = j0 + wj + js * 16 + ll;
    const float bj = bias[j];
#pragma unroll
    for (int ms = 0; ms < 2; ++ms) {
      const int nb = n0 + wm + ms * 16 + (lh << 2);
      float4 xr = *(const float4*)&x[((size_t)b * CC + j) * NN + nb];
      float rr[4] = {acc[ms][js][0] + bj + xr.x, acc[ms][js][1] + bj + xr.y,
                     acc[ms][js][2] + bj + xr.z, acc[ms][js][3] + bj + xr.w};
#pragma unroll
      for (int r = 0; r < 4; ++r)
        RESb[(size_t)(m0 + wm + ms * 16 + (lh << 2) + r) * CC + j] = f2bf(rr[r]);
    }
  }
}

// ---------------------------------------------------------------------------
// GEMM 3 (64x64 tiles): out[b][c][n] = relu( RES @ W3^T + b3 )  (fp32 output)
// ---------------------------------------------------------------------------
__global__ __launch_bounds__(256) void conv_gemm(
    const u16* __restrict__ RESb, const u16* __restrict__ W3b,
    const float* __restrict__ bias, float* __restrict__ out) {
  __shared__ u16 As[64][40];
  __shared__ u16 Ws[64][40];
  const int tid = threadIdx.x;
  const int m0 = blockIdx.x * 64, j0 = blockIdx.y * 64;
  f32x4 acc[2][2] = {};
  gemm_core64(RESb, W3b, m0, j0, As, Ws, acc, tid);

  const int lane = tid & 63, ll = lane & 15, lh = lane >> 4;
  const int wv = tid >> 6;
  const int wm = (wv >> 1) << 5, wj = (wv & 1) << 5;
  const int b = m0 / NN, n0 = m0 % NN;
#pragma unroll
  for (int js = 0; js < 2; ++js) {
    const int j = j0 + wj + js * 16 + ll;
    const float bj = bias[j];
#pragma unroll
    for (int ms = 0; ms < 2; ++ms) {
      const int nb = n0 + wm + ms * 16 + (lh << 2);
      float4 v;
      v.x = fmaxf(acc[ms][js][0] + bj, 0.0f);
      v.y = fmaxf(acc[ms][js][1] + bj, 0.0f);
      v.z = fmaxf(acc[ms][js][2] + bj, 0.0f);
      v.w = fmaxf(acc[ms][js][3] + bj, 0.0f);
      *(float4*)&out[((size_t)b * CC + j) * NN + nb] = v;
    }
  }
}

extern "C" void kernel_launch(void* const* d_in, const int* in_sizes, int n_in,
                              void* d_out, int out_size, void* d_ws, size_t ws_size,
                              hipStream_t stream) {
  const float* x         = (const float*)d_in[0];
  const float* in_proj_w = (const float*)d_in[1];
  const float* in_proj_b = (const float*)d_in[2];
  const float* out_w     = (const float*)d_in[3];
  const float* out_b     = (const float*)d_in[4];
  const float* conv_w    = (const float*)d_in[5];
  const float* conv_b    = (const float*)d_in[6];
  float* out = (float*)d_out;

  u16* wsb = (u16*)d_ws;
  u16* XT   = wsb;                         // [9216][256] bf16
  u16* Qb   = wsb + (size_t)BUF;           // [B,H,N,32]
  u16* Kb   = wsb + (size_t)2 * BUF;       // [B,H,N,32]
  u16* VTb  = wsb + (size_t)3 * BUF;       // [B,H,32,N]
  u16* Ob   = wsb + (size_t)4 * BUF;       // [9216][256]
  u16* RESb = wsb + (size_t)5 * BUF;       // [9216][256]
  u16* W1b  = wsb + (size_t)6 * BUF;       // [768][256]
  u16* W2b  = W1b + 196608;                // [256][256]
  u16* W3b  = W2b + 65536;                 // [256][256]

  prep_kernel<<<dim3(2624), dim3(256), 0, stream>>>(x, in_proj_w, out_w, conv_w,
                                                    XT, W1b, W2b, W3b);
  qkv_gemm<<<dim3(72, 6), dim3(256), 0, stream>>>(XT, W1b, in_proj_b, Qb, Kb, VTb);
  attn_mfma<<<dim3(1152), dim3(256), 0, stream>>>(Qb, Kb, VTb, Ob);
  outproj_gemm<<<dim3(144, 4), dim3(256), 0, stream>>>(Ob, W2b, out_b, x, RESb);
  conv_gemm<<<dim3(144, 4), dim3(256), 0, stream>>>(RESb, W3b, conv_b, out);
}